// Round 2
// baseline (3740.956 us; speedup 1.0000x reference)
//
#include <hip/hip_runtime.h>
#include <hip/hip_bf16.h>

// ZINC GINE inner, round 1: correctness-first f32 (bf16 LDS weights).
// 2-buffer workspace: bufB = h [N,128], bufA = u/aggr/z [N,128]. 204.8MB + 4KB.
// All kernels <= ~37KB static LDS. 8 rows/edges per block iteration.

#define BNEPS 1e-5f

// ---------------- dst[i] = (1+eps)*src[i] ----------------
__global__ __launch_bounds__(256) void k_scale(
    const float* __restrict__ src, const float* __restrict__ epsp, int epsIdx,
    float* __restrict__ dst, int total)
{
    float s = 1.0f + epsp[epsIdx];
    for (int i = blockIdx.x * 256 + threadIdx.x; i < total; i += gridDim.x * 256)
        dst[i] = s * src[i];
}

// ---------------- layer-1 edge kernel (d=28, f32 weights) ----------------
// e = relu(ea@W1[4,28]+b1) @ W2[28,28] + b2 ; m = relu(x[src]+e)*w -> atomic aggr[dst]
__global__ __launch_bounds__(256) void k_edge28(
    const float* __restrict__ x,      // [N,28]
    const int* __restrict__ ei,       // [2,E]
    const float* __restrict__ ea,     // [E,4]
    const float* __restrict__ ew,     // [E]
    const float* __restrict__ W1, const float* __restrict__ b1,
    const float* __restrict__ W2, const float* __restrict__ b2,
    float* __restrict__ aggr,         // [N,28] region (pre-initialized)
    int E)
{
    __shared__ float W1s[4*28], W2s[28*28], b1s[28], b2s[28];
    __shared__ float tbuf[8][28];
    int tid = threadIdx.x;
    for (int i = tid; i < 4*28; i += 256) W1s[i] = W1[i];
    for (int i = tid; i < 28*28; i += 256) W2s[i] = W2[i];
    if (tid < 28) { b1s[tid] = b1[tid]; b2s[tid] = b2[tid]; }
    __syncthreads();

    int sub = tid >> 5;      // 0..7 : edge within group
    int j   = tid & 31;      // 0..31 : column (28 active)
    int numGroups = (E + 7) >> 3;
    for (int gb = blockIdx.x; gb < numGroups; gb += gridDim.x) {
        int e = gb * 8 + sub;
        bool valid = (e < E);
        int src = 0, dst = 0; float w = 0.f, a0 = 0.f, a1 = 0.f, a2 = 0.f, a3 = 0.f;
        if (valid) {
            src = ei[e]; dst = ei[E + e]; w = ew[e];
            const float* eap = ea + (size_t)e * 4;
            a0 = eap[0]; a1 = eap[1]; a2 = eap[2]; a3 = eap[3];
        }
        if (j < 28) {
            float t = a0*W1s[j] + a1*W1s[28+j] + a2*W1s[56+j] + a3*W1s[84+j] + b1s[j];
            tbuf[sub][j] = fmaxf(t, 0.f);
        }
        __syncthreads();
        if (valid && j < 28) {
            float acc = b2s[j];
            #pragma unroll
            for (int i = 0; i < 28; ++i) acc = fmaf(tbuf[sub][i], W2s[i*28 + j], acc);
            float m = fmaxf(x[(size_t)src*28 + j] + acc, 0.f) * w;
            atomicAdd(&aggr[(size_t)dst*28 + j], m);
        }
        __syncthreads();
    }
}

// ---------------- hidden edge kernel (d=128, bf16 W2 in LDS, W1 in regs) ----------------
__global__ __launch_bounds__(256) void k_edge128(
    const float* __restrict__ h,      // [N,128]
    const int* __restrict__ ei,
    const float* __restrict__ ea,
    const float* __restrict__ ew,
    const float* __restrict__ W1,     // [4,128]
    const float* __restrict__ b1,     // [128]
    const float* __restrict__ W2,     // [128,128]
    const float* __restrict__ b2,     // [128]
    float* __restrict__ aggr,         // [N,128] (pre-initialized)
    int E)
{
    __shared__ __hip_bfloat16 Ws[128*128];   // 32KB
    __shared__ float tb[8][128];             // 4KB
    __shared__ float eas[8][4];
    __shared__ float ews[8];
    __shared__ int srcs[8], dsts[8];
    int tid = threadIdx.x;
    for (int i = tid; i < 128*128; i += 256) Ws[i] = __float2bfloat16(W2[i]);
    int j = tid & 127, g = tid >> 7;
    float w1r0 = W1[j], w1r1 = W1[128+j], w1r2 = W1[256+j], w1r3 = W1[384+j];
    float b1j = b1[j], b2j = b2[j];
    __syncthreads();

    int numGroups = (E + 7) >> 3;
    for (int gb = blockIdx.x; gb < numGroups; gb += gridDim.x) {
        int base = gb * 8;
        if (tid < 8) {
            int e = base + tid;
            bool v = (e < E);
            srcs[tid] = v ? ei[e] : 0;
            dsts[tid] = v ? ei[E + e] : 0;
            ews[tid]  = v ? ew[e] : 0.f;
        }
        if (tid < 32) {
            int e = base + (tid >> 2);
            eas[tid >> 2][tid & 3] = (e < E) ? ea[(size_t)e*4 + (tid & 3)] : 0.f;
        }
        __syncthreads();
        #pragma unroll
        for (int q = 0; q < 4; ++q) {
            int el = g*4 + q;
            float t = fmaf(eas[el][0], w1r0, fmaf(eas[el][1], w1r1,
                      fmaf(eas[el][2], w1r2, fmaf(eas[el][3], w1r3, b1j))));
            tb[el][j] = fmaxf(t, 0.f);
        }
        __syncthreads();
        float a0 = b2j, a1 = b2j, a2 = b2j, a3 = b2j;
        const float* t0 = tb[g*4+0];
        const float* t1 = tb[g*4+1];
        const float* t2 = tb[g*4+2];
        const float* t3 = tb[g*4+3];
        #pragma unroll 8
        for (int i = 0; i < 128; ++i) {
            float w = __bfloat162float(Ws[i*128 + j]);
            a0 = fmaf(t0[i], w, a0);
            a1 = fmaf(t1[i], w, a1);
            a2 = fmaf(t2[i], w, a2);
            a3 = fmaf(t3[i], w, a3);
        }
        #pragma unroll
        for (int q = 0; q < 4; ++q) {
            int el = g*4 + q;
            int e = base + el;
            if (e < E) {
                float acc = (q == 0) ? a0 : (q == 1) ? a1 : (q == 2) ? a2 : a3;
                float m = fmaxf(h[(size_t)srcs[el]*128 + j] + acc, 0.f) * ews[el];
                atomicAdd(&aggr[(size_t)dsts[el]*128 + j], m);
            }
        }
        __syncthreads();
    }
}

// ---------------- layer-1 first linear: t = relu(u28 @ W[28,128] + b) ----------------
__global__ __launch_bounds__(256) void k_lin_s(
    const float* __restrict__ src,    // [N,28]
    const float* __restrict__ W,      // [28,128]
    const float* __restrict__ b,
    float* __restrict__ dst,          // [N,128]
    int N)
{
    __shared__ float Ws[28*128];      // 14KB
    __shared__ float ub[8][28];
    int tid = threadIdx.x;
    for (int i = tid; i < 28*128; i += 256) Ws[i] = W[i];
    __syncthreads();
    int j = tid & 127, g = tid >> 7;
    float bj = b[j];
    int numGroups = (N + 7) >> 3;
    for (int gb = blockIdx.x; gb < numGroups; gb += gridDim.x) {
        int base = gb * 8;
        for (int k = tid; k < 8*28; k += 256) {
            int r = k / 28, c = k - r*28;
            int rr = base + r;
            ub[r][c] = (rr < N) ? src[(size_t)rr*28 + c] : 0.f;
        }
        __syncthreads();
        float a0 = bj, a1 = bj, a2 = bj, a3 = bj;
        const float* u0 = ub[g*4+0];
        const float* u1 = ub[g*4+1];
        const float* u2 = ub[g*4+2];
        const float* u3 = ub[g*4+3];
        #pragma unroll
        for (int i = 0; i < 28; ++i) {
            float w = Ws[i*128 + j];
            a0 = fmaf(u0[i], w, a0);
            a1 = fmaf(u1[i], w, a1);
            a2 = fmaf(u2[i], w, a2);
            a3 = fmaf(u3[i], w, a3);
        }
        int r0 = base + g*4;
        if (r0 + 0 < N) dst[(size_t)(r0+0)*128 + j] = fmaxf(a0, 0.f);
        if (r0 + 1 < N) dst[(size_t)(r0+1)*128 + j] = fmaxf(a1, 0.f);
        if (r0 + 2 < N) dst[(size_t)(r0+2)*128 + j] = fmaxf(a2, 0.f);
        if (r0 + 3 < N) dst[(size_t)(r0+3)*128 + j] = fmaxf(a3, 0.f);
        __syncthreads();
    }
}

// ---------------- 128x128 linear; stats==null -> relu out; else raw + BN stats ----------------
// dst may alias src (rows staged to LDS before overwrite).
__global__ __launch_bounds__(256) void k_lin128(
    const float* __restrict__ src,    // [N,128]
    const float* __restrict__ W,      // [128,128]
    const float* __restrict__ b,
    float* __restrict__ dst,          // [N,128]
    float* __restrict__ stats,        // null or [256]
    int N)
{
    __shared__ __hip_bfloat16 Ws[128*128];  // 32KB
    __shared__ float ub[8][128];            // 4KB
    int tid = threadIdx.x;
    for (int i = tid; i < 128*128; i += 256) Ws[i] = __float2bfloat16(W[i]);
    __syncthreads();
    int j = tid & 127, g = tid >> 7;
    float bj = b[j];
    float lsum = 0.f, lsq = 0.f;
    int numGroups = (N + 7) >> 3;
    for (int gb = blockIdx.x; gb < numGroups; gb += gridDim.x) {
        int base = gb * 8;
        #pragma unroll
        for (int k = 0; k < 4; ++k) {
            int idx = tid + k * 256;
            int r = idx >> 7, c = idx & 127;
            int rr = base + r;
            ub[r][c] = (rr < N) ? src[(size_t)rr*128 + c] : 0.f;
        }
        __syncthreads();
        float a0 = bj, a1 = bj, a2 = bj, a3 = bj;
        const float* u0 = ub[g*4+0];
        const float* u1 = ub[g*4+1];
        const float* u2 = ub[g*4+2];
        const float* u3 = ub[g*4+3];
        #pragma unroll 8
        for (int i = 0; i < 128; ++i) {
            float w = __bfloat162float(Ws[i*128 + j]);
            a0 = fmaf(u0[i], w, a0);
            a1 = fmaf(u1[i], w, a1);
            a2 = fmaf(u2[i], w, a2);
            a3 = fmaf(u3[i], w, a3);
        }
        int r0 = base + g*4;
        if (stats) {
            if (r0 + 0 < N) { dst[(size_t)(r0+0)*128 + j] = a0; lsum += a0; lsq = fmaf(a0, a0, lsq); }
            if (r0 + 1 < N) { dst[(size_t)(r0+1)*128 + j] = a1; lsum += a1; lsq = fmaf(a1, a1, lsq); }
            if (r0 + 2 < N) { dst[(size_t)(r0+2)*128 + j] = a2; lsum += a2; lsq = fmaf(a2, a2, lsq); }
            if (r0 + 3 < N) { dst[(size_t)(r0+3)*128 + j] = a3; lsum += a3; lsq = fmaf(a3, a3, lsq); }
        } else {
            if (r0 + 0 < N) dst[(size_t)(r0+0)*128 + j] = fmaxf(a0, 0.f);
            if (r0 + 1 < N) dst[(size_t)(r0+1)*128 + j] = fmaxf(a1, 0.f);
            if (r0 + 2 < N) dst[(size_t)(r0+2)*128 + j] = fmaxf(a2, 0.f);
            if (r0 + 3 < N) dst[(size_t)(r0+3)*128 + j] = fmaxf(a3, 0.f);
        }
        __syncthreads();
    }
    if (stats) {
        atomicAdd(&stats[j], lsum);
        atomicAdd(&stats[128 + j], lsq);
    }
}

// ---------------- BN(train)+relu (+residual): h = [h +] relu(bn(z)) ----------------
__global__ __launch_bounds__(256) void k_bn(
    const float* __restrict__ z, const float* __restrict__ stats,
    const float* __restrict__ g, const float* __restrict__ b,
    float* __restrict__ h, int N, int residual, float invN)
{
    int total = N * 128;
    for (int idx = blockIdx.x * 256 + threadIdx.x; idx < total; idx += gridDim.x * 256) {
        int j = idx & 127;
        float mu  = stats[j] * invN;
        float var = fmaf(stats[128 + j], invN, -mu * mu);
        float sc  = rsqrtf(fmaxf(var, 0.f) + BNEPS) * g[j];
        float v   = fmaxf(fmaf(z[idx] - mu, sc, b[j]), 0.f);
        h[idx] = residual ? (h[idx] + v) : v;
    }
}

// ---------------- masked pool ----------------
__global__ __launch_bounds__(256) void k_pool(
    const float* __restrict__ h, const float* __restrict__ mask,
    const int* __restrict__ s2n, float* __restrict__ out, int N)
{
    int total = N * 128;
    for (int idx = blockIdx.x * 256 + threadIdx.x; idx < total; idx += gridDim.x * 256) {
        int n = idx >> 7, j = idx & 127;
        float mk = mask[n];
        if (mk != 0.f) {
            atomicAdd(&out[(size_t)s2n[n] * 128 + j], h[idx] * mk);
        }
    }
}

extern "C" void kernel_launch(void* const* d_in, const int* in_sizes, int n_in,
                              void* d_out, int out_size, void* d_ws, size_t ws_size,
                              hipStream_t stream) {
    const float* x    = (const float*)d_in[0];
    const int*   ei   = (const int*)d_in[1];
    const float* ea   = (const float*)d_in[2];
    const float* ew   = (const float*)d_in[3];
    const float* mask = (const float*)d_in[4];
    const int*   s2n  = (const int*)d_in[5];
    const float* be1W1 = (const float*)d_in[6];
    const float* be1b1 = (const float*)d_in[7];
    const float* be1W2 = (const float*)d_in[8];
    const float* be1b2 = (const float*)d_in[9];
    const float* m1W1  = (const float*)d_in[10];
    const float* m1b1  = (const float*)d_in[11];
    const float* m1W2  = (const float*)d_in[12];
    const float* m1b2  = (const float*)d_in[13];
    const float* bn1g  = (const float*)d_in[14];
    const float* bn1b  = (const float*)d_in[15];
    const float* eps1  = (const float*)d_in[16];
    const float* beW1  = (const float*)d_in[17]; // [3,4,128]
    const float* beb1  = (const float*)d_in[18]; // [3,128]
    const float* beW2  = (const float*)d_in[19]; // [3,128,128]
    const float* beb2  = (const float*)d_in[20]; // [3,128]
    const float* mW1   = (const float*)d_in[21]; // [3,128,128]
    const float* mb1   = (const float*)d_in[22]; // [3,128]
    const float* mW2   = (const float*)d_in[23]; // [3,128,128]
    const float* mb2   = (const float*)d_in[24]; // [3,128]
    const float* bng   = (const float*)d_in[25]; // [3,128]
    const float* bnb   = (const float*)d_in[26]; // [3,128]
    const float* epsL  = (const float*)d_in[27]; // [3]

    const int N = in_sizes[0] / 28;
    const int E = in_sizes[1] / 2;
    const int S = out_size / 128;
    const float invN = 1.0f / (float)N;

    float* bufB  = (float*)d_ws;                    // h (and layer-1 t/z)
    float* bufA  = bufB + (size_t)N * 128;          // u / aggr / z
    float* stats = bufA + (size_t)N * 128;          // [4*256]

    hipMemsetAsync(stats, 0, 4 * 256 * sizeof(float), stream);

    const int GRID_G  = 1024;
    const int GRID_E  = 2048;
    const int GRID_EL = 2048;

    // ---- layer 1 (28 -> 128): u28 in bufA, t/z in bufB, h in bufB ----
    k_scale<<<512, 256, 0, stream>>>(x, eps1, 0, bufA, N * 28);
    k_edge28<<<GRID_E, 256, 0, stream>>>(x, ei, ea, ew, be1W1, be1b1, be1W2, be1b2, bufA, E);
    k_lin_s<<<GRID_G, 256, 0, stream>>>(bufA, m1W1, m1b1, bufB, N);
    k_lin128<<<GRID_G, 256, 0, stream>>>(bufB, m1W2, m1b2, bufB, stats, N);
    k_bn<<<GRID_EL, 256, 0, stream>>>(bufB, stats, bn1g, bn1b, bufB, N, 0, invN);

    // ---- layers 2..4: h in bufB, u/aggr/t/z in bufA ----
    for (int l = 0; l < 3; ++l) {
        k_scale<<<GRID_EL, 256, 0, stream>>>(bufB, epsL, l, bufA, N * 128);
        k_edge128<<<GRID_E, 256, 0, stream>>>(bufB, ei, ea, ew,
            beW1 + (size_t)l * 4 * 128, beb1 + (size_t)l * 128,
            beW2 + (size_t)l * 128 * 128, beb2 + (size_t)l * 128, bufA, E);
        k_lin128<<<GRID_G, 256, 0, stream>>>(bufA,
            mW1 + (size_t)l * 128 * 128, mb1 + (size_t)l * 128, bufA, nullptr, N);
        k_lin128<<<GRID_G, 256, 0, stream>>>(bufA,
            mW2 + (size_t)l * 128 * 128, mb2 + (size_t)l * 128, bufA,
            stats + 256 * (l + 1), N);
        k_bn<<<GRID_EL, 256, 0, stream>>>(bufA, stats + 256 * (l + 1),
            bng + (size_t)l * 128, bnb + (size_t)l * 128, bufB, N, 1, invN);
    }

    // ---- masked segment-sum pool ----
    hipMemsetAsync(d_out, 0, (size_t)S * 128 * sizeof(float), stream);
    k_pool<<<GRID_EL, 256, 0, stream>>>(bufB, mask, s2n, (float*)d_out, N);
}

// Round 3
// 1855.620 us; speedup vs baseline: 2.0160x; 2.0160x over previous
//
#include <hip/hip_runtime.h>
#include <hip/hip_bf16.h>

// ZINC GINE inner, round 2: MFMA bf16 for all 128x128 GEMMs.
// f32 aggregation/BN/residual/pool. Weights pre-transposed to bf16 W^T once.

#define BNEPS 1e-5f
#define LDA 136   // 128 + 8 shorts pad (272B rows -> balanced LDS banks)

typedef __attribute__((ext_vector_type(8))) short bf16x8;
typedef __attribute__((ext_vector_type(4))) float f32x4;

__device__ inline short f2bf(float f) {
    __hip_bfloat16 h = __float2bfloat16(f);
    return *reinterpret_cast<short*>(&h);
}

// ---------------- prep: transpose 10 f32 [128,128] weights -> bf16 W^T ----------------
// mat order: 0: m1W2 ; 1+3l+{0,1,2}: beW2[l], mW1[l], mW2[l]
__global__ __launch_bounds__(256) void k_prep(
    const float* __restrict__ m1W2, const float* __restrict__ beW2,
    const float* __restrict__ mW1, const float* __restrict__ mW2,
    short* __restrict__ out)
{
    __shared__ float tileS[64][65];
    int b = blockIdx.x, mat = b >> 2, t = b & 3;
    const float* Wsrc;
    if (mat == 0) Wsrc = m1W2;
    else {
        int l = (mat - 1) / 3, which = (mat - 1) % 3;
        Wsrc = (which == 0) ? beW2 + (size_t)l * 16384
             : (which == 1) ? mW1 + (size_t)l * 16384
             :                mW2 + (size_t)l * 16384;
    }
    short* dst = out + (size_t)mat * 16384;
    int tr = (t >> 1) * 64, tc = (t & 1) * 64;   // k-offset, n-offset
    for (int i = threadIdx.x; i < 4096; i += 256) {
        int r = i >> 6, c = i & 63;
        tileS[r][c] = Wsrc[(size_t)(tr + r) * 128 + (tc + c)];
    }
    __syncthreads();
    for (int i = threadIdx.x; i < 4096; i += 256) {
        int n = i >> 6, k = i & 63;
        dst[(size_t)(tc + n) * 128 + (tr + k)] = f2bf(tileS[k][n]);  // W^T[n][k]=W[k][n]
    }
}

// ---------------- u28 = (1+eps)*x ----------------
__global__ __launch_bounds__(256) void k_scale(
    const float* __restrict__ src, const float* __restrict__ epsp,
    float* __restrict__ dst, int total)
{
    float s = 1.0f + epsp[0];
    for (int i = blockIdx.x * 256 + threadIdx.x; i < total; i += gridDim.x * 256)
        dst[i] = s * src[i];
}

// ---------------- layer-1 edge kernel (d=28, f32, unchanged) ----------------
__global__ __launch_bounds__(256) void k_edge28(
    const float* __restrict__ x, const int* __restrict__ ei,
    const float* __restrict__ ea, const float* __restrict__ ew,
    const float* __restrict__ W1, const float* __restrict__ b1,
    const float* __restrict__ W2, const float* __restrict__ b2,
    float* __restrict__ aggr, int E)
{
    __shared__ float W1s[4*28], W2s[28*28], b1s[28], b2s[28];
    __shared__ float tbuf[8][28];
    int tid = threadIdx.x;
    for (int i = tid; i < 4*28; i += 256) W1s[i] = W1[i];
    for (int i = tid; i < 28*28; i += 256) W2s[i] = W2[i];
    if (tid < 28) { b1s[tid] = b1[tid]; b2s[tid] = b2[tid]; }
    __syncthreads();
    int sub = tid >> 5, j = tid & 31;
    int numGroups = (E + 7) >> 3;
    for (int gb = blockIdx.x; gb < numGroups; gb += gridDim.x) {
        int e = gb * 8 + sub;
        bool valid = (e < E);
        int src = 0, dst = 0; float w = 0.f, a0 = 0.f, a1 = 0.f, a2 = 0.f, a3 = 0.f;
        if (valid) {
            src = ei[e]; dst = ei[E + e]; w = ew[e];
            const float* eap = ea + (size_t)e * 4;
            a0 = eap[0]; a1 = eap[1]; a2 = eap[2]; a3 = eap[3];
        }
        if (j < 28) {
            float t = a0*W1s[j] + a1*W1s[28+j] + a2*W1s[56+j] + a3*W1s[84+j] + b1s[j];
            tbuf[sub][j] = fmaxf(t, 0.f);
        }
        __syncthreads();
        if (valid && j < 28) {
            float acc = b2s[j];
            #pragma unroll
            for (int i = 0; i < 28; ++i) acc = fmaf(tbuf[sub][i], W2s[i*28 + j], acc);
            float m = fmaxf(x[(size_t)src*28 + j] + acc, 0.f) * w;
            atomicAdd(&aggr[(size_t)dst*28 + j], m);
        }
        __syncthreads();
    }
}

// ---------------- layer-1 first linear (28->128, f32, unchanged) ----------------
__global__ __launch_bounds__(256) void k_lin_s(
    const float* __restrict__ src, const float* __restrict__ W,
    const float* __restrict__ b, float* __restrict__ dst, int N)
{
    __shared__ float Ws[28*128];
    __shared__ float ub[8][28];
    int tid = threadIdx.x;
    for (int i = tid; i < 28*128; i += 256) Ws[i] = W[i];
    __syncthreads();
    int j = tid & 127, g = tid >> 7;
    float bj = b[j];
    int numGroups = (N + 7) >> 3;
    for (int gb = blockIdx.x; gb < numGroups; gb += gridDim.x) {
        int base = gb * 8;
        for (int k = tid; k < 8*28; k += 256) {
            int r = k / 28, c = k - r*28;
            int rr = base + r;
            ub[r][c] = (rr < N) ? src[(size_t)rr*28 + c] : 0.f;
        }
        __syncthreads();
        float a0 = bj, a1 = bj, a2 = bj, a3 = bj;
        const float* u0 = ub[g*4+0]; const float* u1 = ub[g*4+1];
        const float* u2 = ub[g*4+2]; const float* u3 = ub[g*4+3];
        #pragma unroll
        for (int i = 0; i < 28; ++i) {
            float w = Ws[i*128 + j];
            a0 = fmaf(u0[i], w, a0); a1 = fmaf(u1[i], w, a1);
            a2 = fmaf(u2[i], w, a2); a3 = fmaf(u3[i], w, a3);
        }
        int r0 = base + g*4;
        if (r0 + 0 < N) dst[(size_t)(r0+0)*128 + j] = fmaxf(a0, 0.f);
        if (r0 + 1 < N) dst[(size_t)(r0+1)*128 + j] = fmaxf(a1, 0.f);
        if (r0 + 2 < N) dst[(size_t)(r0+2)*128 + j] = fmaxf(a2, 0.f);
        if (r0 + 3 < N) dst[(size_t)(r0+3)*128 + j] = fmaxf(a3, 0.f);
        __syncthreads();
    }
}

// ---------------- MFMA node GEMM: dst = act(src @ W + b), optional BN stats ----------------
// W passed as bf16 W^T [n][k]. dst may alias src. 64-row tiles, 4 waves.
__global__ __launch_bounds__(256) void k_mm128(
    const float* __restrict__ src, const short* __restrict__ Wt,
    const float* __restrict__ bias, float* __restrict__ dst,
    float* __restrict__ stats, int N, int relu)
{
    __shared__ short Bs[128 * LDA];
    __shared__ short As[64 * LDA];
    __shared__ float sstat[256];
    int tid = threadIdx.x;
    for (int i = tid; i < 2048; i += 256) {   // 2048 * 8 shorts = 16384
        int n = (i * 8) >> 7, k = (i * 8) & 127;
        *(bf16x8*)&Bs[n * LDA + k] = *(const bf16x8*)&Wt[i * 8];
    }
    sstat[tid] = 0.f;
    __syncthreads();

    int w = tid >> 6, lane = tid & 63;
    int l15 = lane & 15, quad = lane >> 4;
    float lsum[8], lsq[8];
    #pragma unroll
    for (int nt = 0; nt < 8; ++nt) { lsum[nt] = 0.f; lsq[nt] = 0.f; }

    int numTiles = (N + 63) >> 6;
    for (int tile = blockIdx.x; tile < numTiles; tile += gridDim.x) {
        int base = tile * 64;
        __syncthreads();   // protect As from previous iteration readers
        #pragma unroll
        for (int r8 = 0; r8 < 8; ++r8) {
            int row = (tid >> 5) + r8 * 8;
            int col = (tid & 31) * 4;
            int rr = base + row;
            float4 v = (rr < N) ? *(const float4*)&src[(size_t)rr * 128 + col]
                                : make_float4(0.f, 0.f, 0.f, 0.f);
            short4 s4; s4.x = f2bf(v.x); s4.y = f2bf(v.y); s4.z = f2bf(v.z); s4.w = f2bf(v.w);
            *(short4*)&As[row * LDA + col] = s4;
        }
        __syncthreads();
        f32x4 acc[8];
        #pragma unroll
        for (int nt = 0; nt < 8; ++nt) acc[nt] = (f32x4){0.f, 0.f, 0.f, 0.f};
        #pragma unroll
        for (int kt = 0; kt < 4; ++kt) {
            bf16x8 af = *(bf16x8*)&As[(w * 16 + l15) * LDA + kt * 32 + quad * 8];
            #pragma unroll
            for (int nt = 0; nt < 8; ++nt) {
                bf16x8 bf = *(bf16x8*)&Bs[(nt * 16 + l15) * LDA + kt * 32 + quad * 8];
                acc[nt] = __builtin_amdgcn_mfma_f32_16x16x32_bf16(af, bf, acc[nt], 0, 0, 0);
            }
        }
        int row0 = base + w * 16 + quad * 4;
        #pragma unroll
        for (int nt = 0; nt < 8; ++nt) {
            int col = nt * 16 + l15;
            float bc = bias[col];
            #pragma unroll
            for (int r = 0; r < 4; ++r) {
                int row = row0 + r;
                if (row < N) {
                    float z = acc[nt][r] + bc;
                    if (relu) z = fmaxf(z, 0.f);
                    dst[(size_t)row * 128 + col] = z;
                    lsum[nt] += z; lsq[nt] = fmaf(z, z, lsq[nt]);
                }
            }
        }
    }
    if (stats) {
        #pragma unroll
        for (int nt = 0; nt < 8; ++nt) {
            int col = nt * 16 + l15;
            atomicAdd(&sstat[col], lsum[nt]);
            atomicAdd(&sstat[128 + col], lsq[nt]);
        }
        __syncthreads();
        atomicAdd(&stats[tid], sstat[tid]);
    }
}

// ---------------- MFMA edge kernel: e-MLP + message + scatter, fused ----------------
__global__ __launch_bounds__(256) void k_edge_mm(
    const float* __restrict__ h,      // [N,128]
    const int* __restrict__ ei, const float* __restrict__ ea, const float* __restrict__ ew,
    const float* __restrict__ W1, const float* __restrict__ b1,   // f32 [4,128],[128]
    const short* __restrict__ W2t,    // bf16 W2^T [n][k]
    const float* __restrict__ b2,
    float* __restrict__ aggr, int E)
{
    __shared__ short Bs[128 * LDA];
    __shared__ short As[64 * LDA];
    __shared__ float eas[64 * 4];
    __shared__ float ews_s[64];
    __shared__ int srcs[64], dsts[64];
    int tid = threadIdx.x;
    for (int i = tid; i < 2048; i += 256) {
        int n = (i * 8) >> 7, k = (i * 8) & 127;
        *(bf16x8*)&Bs[n * LDA + k] = *(const bf16x8*)&W2t[i * 8];
    }
    int j = tid & 127, half = tid >> 7;
    float w10 = W1[j], w11 = W1[128 + j], w12 = W1[256 + j], w13 = W1[384 + j];
    float b1j = b1[j];
    int w = tid >> 6, lane = tid & 63;
    int l15 = lane & 15, quad = lane >> 4;
    __syncthreads();

    int numTiles = (E + 63) >> 6;
    for (int tile = blockIdx.x; tile < numTiles; tile += gridDim.x) {
        int base = tile * 64;
        __syncthreads();   // protect As/eas/meta from previous iteration readers
        if (tid < 64) {
            int e = base + tid; bool v = (e < E);
            srcs[tid] = v ? ei[e] : 0;
            dsts[tid] = v ? ei[E + e] : 0;
            ews_s[tid] = v ? ew[e] : 0.f;
        }
        {
            int e = base + (tid >> 2);
            eas[tid] = (e < E) ? ea[(size_t)e * 4 + (tid & 3)] : 0.f;
        }
        __syncthreads();
        #pragma unroll
        for (int q = 0; q < 32; ++q) {
            int e = half * 32 + q;
            float t = fmaf(eas[e*4+0], w10, fmaf(eas[e*4+1], w11,
                      fmaf(eas[e*4+2], w12, fmaf(eas[e*4+3], w13, b1j))));
            As[e * LDA + j] = f2bf(fmaxf(t, 0.f));
        }
        __syncthreads();
        f32x4 acc[8];
        #pragma unroll
        for (int nt = 0; nt < 8; ++nt) acc[nt] = (f32x4){0.f, 0.f, 0.f, 0.f};
        #pragma unroll
        for (int kt = 0; kt < 4; ++kt) {
            bf16x8 af = *(bf16x8*)&As[(w * 16 + l15) * LDA + kt * 32 + quad * 8];
            #pragma unroll
            for (int nt = 0; nt < 8; ++nt) {
                bf16x8 bf = *(bf16x8*)&Bs[(nt * 16 + l15) * LDA + kt * 32 + quad * 8];
                acc[nt] = __builtin_amdgcn_mfma_f32_16x16x32_bf16(af, bf, acc[nt], 0, 0, 0);
            }
        }
        int er0 = w * 16 + quad * 4;
        #pragma unroll
        for (int nt = 0; nt < 8; ++nt) {
            int col = nt * 16 + l15;
            float b2c = b2[col];
            #pragma unroll
            for (int r = 0; r < 4; ++r) {
                int el = er0 + r;
                int e = base + el;
                if (e < E) {
                    float evv = acc[nt][r] + b2c;
                    float m = fmaxf(h[(size_t)srcs[el] * 128 + col] + evv, 0.f) * ews_s[el];
                    atomicAdd(&aggr[(size_t)dsts[el] * 128 + col], m);
                }
            }
        }
    }
}

// ---------------- BN(train)+relu (+residual) ; optional u-out or fused pool ----------------
__global__ __launch_bounds__(256) void k_bn(
    const float* __restrict__ z, const float* __restrict__ stats,
    const float* __restrict__ g, const float* __restrict__ b,
    float* __restrict__ h, float* __restrict__ uout,
    const float* __restrict__ epsp, int epsIdx,
    const float* __restrict__ mask, const int* __restrict__ s2n,
    float* __restrict__ pout,
    int N, int residual, float invN)
{
    float s = uout ? (1.0f + epsp[epsIdx]) : 0.f;
    int total = N * 128;
    for (int idx = blockIdx.x * 256 + threadIdx.x; idx < total; idx += gridDim.x * 256) {
        int j = idx & 127;
        float mu  = stats[j] * invN;
        float var = fmaf(stats[128 + j], invN, -mu * mu);
        float sc  = rsqrtf(fmaxf(var, 0.f) + BNEPS) * g[j];
        float v   = fmaxf(fmaf(z[idx] - mu, sc, b[j]), 0.f);
        float hn  = residual ? (h[idx] + v) : v;
        if (pout) {
            int n = idx >> 7;
            float mk = mask[n];
            if (mk != 0.f) atomicAdd(&pout[(size_t)s2n[n] * 128 + j], hn * mk);
        } else {
            h[idx] = hn;
            if (uout) uout[idx] = s * hn;
        }
    }
}

extern "C" void kernel_launch(void* const* d_in, const int* in_sizes, int n_in,
                              void* d_out, int out_size, void* d_ws, size_t ws_size,
                              hipStream_t stream) {
    const float* x    = (const float*)d_in[0];
    const int*   ei   = (const int*)d_in[1];
    const float* ea   = (const float*)d_in[2];
    const float* ew   = (const float*)d_in[3];
    const float* mask = (const float*)d_in[4];
    const int*   s2n  = (const int*)d_in[5];
    const float* be1W1 = (const float*)d_in[6];
    const float* be1b1 = (const float*)d_in[7];
    const float* be1W2 = (const float*)d_in[8];
    const float* be1b2 = (const float*)d_in[9];
    const float* m1W1  = (const float*)d_in[10];
    const float* m1b1  = (const float*)d_in[11];
    const float* m1W2  = (const float*)d_in[12];
    const float* m1b2  = (const float*)d_in[13];
    const float* bn1g  = (const float*)d_in[14];
    const float* bn1b  = (const float*)d_in[15];
    const float* eps1  = (const float*)d_in[16];
    const float* beW1  = (const float*)d_in[17];
    const float* beb1  = (const float*)d_in[18];
    const float* beW2  = (const float*)d_in[19];
    const float* beb2  = (const float*)d_in[20];
    const float* mW1   = (const float*)d_in[21];
    const float* mb1   = (const float*)d_in[22];
    const float* mW2   = (const float*)d_in[23];
    const float* mb2   = (const float*)d_in[24];
    const float* bng   = (const float*)d_in[25];
    const float* bnb   = (const float*)d_in[26];
    const float* epsL  = (const float*)d_in[27];

    const int N = in_sizes[0] / 28;
    const int E = in_sizes[1] / 2;
    const int S = out_size / 128;
    const float invN = 1.0f / (float)N;

    float* bufB  = (float*)d_ws;                    // h (and layer-1 t/z)
    float* bufA  = bufB + (size_t)N * 128;          // u / aggr / z
    float* stats = bufA + (size_t)N * 128;          // [4*256]
    short* wts   = (short*)(stats + 4 * 256);       // 10 * 16384 bf16 W^T

    hipMemsetAsync(stats, 0, 4 * 256 * sizeof(float), stream);
    hipMemsetAsync(d_out, 0, (size_t)S * 128 * sizeof(float), stream);
    k_prep<<<40, 256, 0, stream>>>(m1W2, beW2, mW1, mW2, wts);

    const short* wt_m1W2 = wts;
    auto wt_be = [&](int l) { return wts + (size_t)(1 + 3 * l + 0) * 16384; };
    auto wt_m1 = [&](int l) { return wts + (size_t)(1 + 3 * l + 1) * 16384; };
    auto wt_m2 = [&](int l) { return wts + (size_t)(1 + 3 * l + 2) * 16384; };

    // ---- layer 1 (28 -> 128) ----
    k_scale<<<512, 256, 0, stream>>>(x, eps1, bufA, N * 28);
    k_edge28<<<2048, 256, 0, stream>>>(x, ei, ea, ew, be1W1, be1b1, be1W2, be1b2, bufA, E);
    k_lin_s<<<1024, 256, 0, stream>>>(bufA, m1W1, m1b1, bufB, N);
    k_mm128<<<768, 256, 0, stream>>>(bufB, wt_m1W2, m1b2, bufB, stats, N, 0);
    k_bn<<<2048, 256, 0, stream>>>(bufB, stats, bn1g, bn1b, bufB, bufA, epsL, 0,
                                   nullptr, nullptr, nullptr, N, 0, invN);

    // ---- layers 2..4 ----
    for (int l = 0; l < 3; ++l) {
        k_edge_mm<<<1536, 256, 0, stream>>>(bufB, ei, ea, ew,
            beW1 + (size_t)l * 512, beb1 + (size_t)l * 128,
            wt_be(l), beb2 + (size_t)l * 128, bufA, E);
        k_mm128<<<768, 256, 0, stream>>>(bufA, wt_m1(l), mb1 + (size_t)l * 128,
                                         bufA, nullptr, N, 1);
        k_mm128<<<768, 256, 0, stream>>>(bufA, wt_m2(l), mb2 + (size_t)l * 128,
                                         bufA, stats + 256 * (l + 1), N, 0);
        if (l < 2) {
            k_bn<<<2048, 256, 0, stream>>>(bufA, stats + 256 * (l + 1),
                bng + (size_t)l * 128, bnb + (size_t)l * 128,
                bufB, bufA, epsL, l + 1, nullptr, nullptr, nullptr, N, 1, invN);
        } else {
            k_bn<<<2048, 256, 0, stream>>>(bufA, stats + 256 * (l + 1),
                bng + (size_t)l * 128, bnb + (size_t)l * 128,
                bufB, nullptr, epsL, 0, mask, s2n, (float*)d_out, N, 1, invN);
        }
    }
}